// Round 2
// baseline (114.646 us; speedup 1.0000x reference)
//
#include <hip/hip_runtime.h>

// Emphasis via STFT-LFilter, collapsed to closed form:
//   interior: y[i] = x[i] - alpha * R[i%256] * x[i-1]
//   tail (last 256/row): y[i] = cAt[m]*x[i] + cBt[m]*x[i-1]  (includes 1e-8 wsum clamp)
// with w[n] = sin^2(pi*n/512) (periodic Hann), rows independent, x[-1]=0.

constexpr int T_ROW = 1 << 21;     // 2097152 samples per (B,C) row
constexpr float ALPHA_C = 0.85f;

__global__ __launch_bounds__(256) void emphasis_kernel(
    const float* __restrict__ x, float* __restrict__ y, int nvec_total)
{
    __shared__ float sB[256];    // interior: y = x[i] + sB[m]*x[i-1]
    __shared__ float sAt[256];   // tail:     y = sAt[m]*x[i] + sBt[m]*x[i-1]
    __shared__ float sBt[256];

    {
        const int m = threadIdx.x;            // block size is exactly 256
        const float fm = (float)m;
        // w[n] = 0.5 - 0.5*cos(2*pi*n/512) = sin^2(pi*n/512)
        const float s    = sinpif(fm * (1.0f / 512.0f));
        const float c    = cospif(fm * (1.0f / 512.0f));
        const float wm    = s * s;            // w[m]        (exactly 0 at m=0)
        const float wm256 = c * c;            // w[m+256]
        const float s1    = sinpif((fm - 1.0f) * (1.0f / 512.0f));
        const float wm1   = s1 * s1;          // w[m-1]  (m=0: killed by wm=0)
        const float s255  = sinpif((fm + 255.0f) * (1.0f / 512.0f));
        const float wm255 = s255 * s255;      // w[m+255]

        const float A  = wm * wm + wm256 * wm256;        // wsum interior (>=0.5)
        const float Bc = wm * wm1 + wm256 * wm255;
        sB[m] = (-ALPHA_C * Bc) / fmaxf(A, 1e-8f);

        const float wn2 = wm256 * wm256;                 // wsum tail (clamp matters @ m=255)
        const float d   = fmaxf(wn2, 1e-8f);
        sAt[m] = wn2 / d;
        sBt[m] = (-ALPHA_C * wm256 * wm255) / d;
    }
    __syncthreads();

    const int stride = gridDim.x * blockDim.x;
    for (int v = blockIdx.x * blockDim.x + threadIdx.x; v < nvec_total; v += stride) {
        const long long i = (long long)v * 4;
        const int irow = (int)(i & (long long)(T_ROW - 1));     // index within row
        const float4 xv = *reinterpret_cast<const float4*>(x + i);
        const float xm1 = (irow == 0) ? 0.0f : x[i - 1];        // cache-hit scalar load
        const int m = irow & 255;                               // vec4 never straddles %256
        float4 out;
        if (irow >= T_ROW - 256) {                              // wave-uniform in practice
            out.x = sAt[m + 0] * xv.x + sBt[m + 0] * xm1;
            out.y = sAt[m + 1] * xv.y + sBt[m + 1] * xv.x;
            out.z = sAt[m + 2] * xv.z + sBt[m + 2] * xv.y;
            out.w = sAt[m + 3] * xv.w + sBt[m + 3] * xv.z;
        } else {
            out.x = xv.x + sB[m + 0] * xm1;
            out.y = xv.y + sB[m + 1] * xv.x;
            out.z = xv.z + sB[m + 2] * xv.y;
            out.w = xv.w + sB[m + 3] * xv.z;
        }
        *reinterpret_cast<float4*>(y + i) = out;
    }
}

extern "C" void kernel_launch(void* const* d_in, const int* in_sizes, int n_in,
                              void* d_out, int out_size, void* d_ws, size_t ws_size,
                              hipStream_t stream) {
    const float* x = (const float*)d_in[0];
    float* y = (float*)d_out;
    const int nvec = out_size / 4;          // 8*2097152/4 = 4194304 float4's
    const int block = 256;
    int grid = (nvec + block - 1) / block;
    if (grid > 2048) grid = 2048;           // grid-stride the rest
    emphasis_kernel<<<grid, block, 0, stream>>>(x, y, nvec);
}